// Round 4
// baseline (113.454 us; speedup 1.0000x reference)
//
#include <hip/hip_runtime.h>
#include <hip/hip_bf16.h>
#include <stdint.h>

// SimpleVectorQuantizer: vecs [16,32,128,64] f32, codebook [512,64] f32.
// Outputs (flat f32): vecs_hat [65536*64], z [65536] (as float), l_commit, l_codebook.
//
// Round 15: r11/r13/r14 isolated the bottleneck as TOTAL B-stream traffic
// (each wave privately streamed the 139KB B image via L1/L2: 2048 waves x
// 139KB x ~1.7 line-split waste ~ 480MB; r13's 2x waves cost exactly the
// predicted extra traffic; r14's depth-3 pipeline only trimmed latency).
// Now: LDS-shared B stream. Each block stages each 4KB tile ONCE via
// global_load_lds (1 instr/wave/tile), 3-buffer rotation, ONE raw s_barrier
// per tile with counted s_waitcnt vmcnt(1) (never drained -- __syncthreads'
// vmcnt(0) drain is what killed r6-r10's staged-LDS attempt). 4x cut in
// L2 B-traffic. Rows packed to 256B (4KB tiles, line-aligned; kills the
// 272B-stride line-split waste). Bank conflicts handled per rule #21:
// bimg is stored PRE-SWIZZLED (col ^ ((row&7)<<4)) so linear gload_lds
// dests are correct and ds_read applies the same XOR -> uniform 8 lanes
// per bank group (conflict-free b128). Numerics (hi/lo bf16 MFMA chain,
// -csq/2 C-init, packed-key merge, in-block exact-f64 rescue, gather)
// byte-identical to the r8-r14 absmax-0 path.

#define VQ_K 64
#define VQ_S 512
#define NTHREADS 256                     // 4 waves
#define MT 2                             // m-tiles per wave -> 32 vectors/wave
#define VPB 128                          // vectors per block
#define NTILES 32                        // 512 codewords / 16 per tile
#define ROWB 256                         // B row: 64 hi bf16 + 64 lo bf16 (packed)
#define TILEB 4096                       // 16 rows x 256B
#define CSQ_OFF (VQ_S * ROWB)            // 131072
#define CELL 7.62939453125e-6f           // f32 ulp at ref-score magnitude ~64
#define GAP_THRESH (8.0f * CELL)

typedef __attribute__((ext_vector_type(8))) short bf16x8;
typedef __attribute__((ext_vector_type(4))) float f32x4;

static __device__ __forceinline__ unsigned short f2bf_rne(float f) {
    unsigned u = __float_as_uint(f);
    unsigned r = (u + 0x7fffu + ((u >> 16) & 1u)) >> 16;
    return (unsigned short)r;
}
static __device__ __forceinline__ float bf2f(unsigned short h) {
    return __uint_as_float(((unsigned)h) << 16);
}
static __device__ __forceinline__ void gload_lds16(const void* g, void* l) {
    __builtin_amdgcn_global_load_lds(
        (const __attribute__((address_space(1))) unsigned int*)g,
        (__attribute__((address_space(3))) unsigned int*)l, 16, 0, 0);
}

// K1: one wave per codebook row; lane k handles element k. Also zeroes loss.
// Stores the B image PRE-SWIZZLED: logical (row r, col c) at r*256 + (c ^ ((r&7)<<4)).
__global__ __launch_bounds__(256, 1) void vq_prep(
    const float* __restrict__ cb, unsigned char* __restrict__ bimg,
    float* __restrict__ out_loss) {
    if (blockIdx.x == 0 && threadIdx.x == 0) { out_loss[0] = 0.f; out_loss[1] = 0.f; }
    const int lane = threadIdx.x & 63;
    const int row = blockIdx.x * 4 + (threadIdx.x >> 6);
    float c = cb[(size_t)row * VQ_K + lane];
    double d = (double)c * (double)c;
#pragma unroll
    for (int off = 1; off <= 32; off <<= 1) d += __shfl_xor(d, off, 64);
    unsigned short hi = f2bf_rne(c);
    unsigned short lo = f2bf_rne(c - bf2f(hi));
    const int t = row >> 4;
    const int r = row & 15;
    const int xr = (r & 7) << 4;
    unsigned char* tb = bimg + (size_t)t * TILEB + r * ROWB;
    *(unsigned short*)(tb + ((2 * lane) ^ xr)) = hi;          // hi block: cols [0,128)
    *(unsigned short*)(tb + ((128 + 2 * lane) ^ xr)) = lo;    // lo block: cols [128,256)
    if (lane == 0) ((float*)(bimg + CSQ_OFF))[row] = (float)d;
}

// K2: LDS-shared MFMA scan + in-block exact rescue. 4 waves x 2 m-tiles.
__global__ __launch_bounds__(NTHREADS, 2) void vq_mfma(
    const float* __restrict__ vecs, const float* __restrict__ codebook,
    const unsigned char* __restrict__ bimg,
    float* __restrict__ out_hat, float* __restrict__ out_z,
    float* __restrict__ out_loss, float inv_n) {
    __shared__ __align__(16) unsigned char bstage[3 * TILEB];  // 3-buffer B tiles
    __shared__ float csq_sh[VQ_S];       // exact csq (rescue)
    __shared__ float csqn2_sh[VQ_S];     // -csq/2 (C-init for the scan)
    __shared__ float vsq_all[VPB];
    __shared__ int zsh[VPB];
    __shared__ int rlist[VPB];
    __shared__ int rn;
    __shared__ float loss_sh;

    const int tid = threadIdx.x;
    const int wave = tid >> 6;                    // 0..3
    const int lane = tid & 63;
    const int m = lane & 15;
    const int q = lane >> 4;
    const int blockbase = blockIdx.x * VPB;
    const int wavebase = blockbase + wave * 32;   // 32 vectors per wave

    if (tid == 0) { rn = 0; loss_sh = 0.f; }
    // Stage csq tables once.
    {
        const float* csqg = (const float*)(bimg + CSQ_OFF);
#pragma unroll
        for (int i = tid; i < VQ_S; i += NTHREADS) {
            float c = csqg[i];
            csq_sh[i] = c;
            csqn2_sh[i] = -0.5f * c;
        }
    }
    // Prologue stage: tiles 0,1 -> buf0,buf1 (drained by the syncthreads below).
    {
        const unsigned char* g0 = bimg + wave * 1024 + lane * 16;
        unsigned char* l0 = &bstage[wave * 1024];
        gload_lds16(g0, l0);
        gload_lds16(g0 + TILEB, l0 + TILEB);
    }

    // ---- A fragments (bf16 split) + exact vsq ----
    bf16x8 ah1[MT], ah2[MT], al1[MT], al2[MT];
#pragma unroll
    for (int mt = 0; mt < MT; ++mt) {
        const float* vp = vecs + (size_t)(wavebase + mt * 16 + m) * VQ_K + q * 8;
        float4 a0 = ((const float4*)vp)[0];
        float4 a1 = ((const float4*)vp)[1];
        float4 b0 = ((const float4*)(vp + 32))[0];
        float4 b1 = ((const float4*)(vp + 32))[1];
        float w1[8] = {a0.x, a0.y, a0.z, a0.w, a1.x, a1.y, a1.z, a1.w};
        float w2[8] = {b0.x, b0.y, b0.z, b0.w, b1.x, b1.y, b1.z, b1.w};
        double p = 0.0;
#pragma unroll
        for (int j = 0; j < 8; ++j) {
            double d1 = (double)w1[j], d2 = (double)w2[j];
            p = fma(d1, d1, p); p = fma(d2, d2, p);
        }
        p += __shfl_xor(p, 16, 64);
        p += __shfl_xor(p, 32, 64);
        if (q == 0) vsq_all[wave * 32 + mt * 16 + m] = (float)p;
#pragma unroll
        for (int j = 0; j < 8; ++j) {
            unsigned short h1 = f2bf_rne(w1[j]);
            unsigned short h2 = f2bf_rne(w2[j]);
            ah1[mt][j] = (short)h1;
            ah2[mt][j] = (short)h2;
            al1[mt][j] = (short)f2bf_rne(w1[j] - bf2f(h1));
            al2[mt][j] = (short)f2bf_rne(w2[j] - bf2f(h2));
        }
    }
    __syncthreads();   // drains prologue stages too: tiles 0,1 resident, vmcnt=0

    // ---- K-loop: 1 raw barrier/tile, counted vmcnt, 3-buffer LDS rotation ----
    float t1u[8], t2u[8];
    int t1i[8];
#pragma unroll
    for (int st = 0; st < 8; ++st) { t1u[st] = -3.4e38f; t2u[st] = -3.4e38f; t1i[st] = 0; }
    const f32x4 zero4 = {0.f, 0.f, 0.f, 0.f};

    const unsigned char* gsrc = bimg + wave * 1024 + lane * 16;
    const int xm = (m & 7) << 4;
    int cur = 0, stg = 2;

#pragma unroll 4
    for (int t = 0; t < NTILES; ++t) {
        // my stage of tile t done (tile t+1 stays in flight); rendezvous.
        asm volatile("s_waitcnt vmcnt(1)" ::: "memory");
        __builtin_amdgcn_s_barrier();
        __builtin_amdgcn_sched_barrier(0);
        // stage tile (t+2)&31 into buf[stg] (= buffer read at iter t-1: safe)
        gload_lds16(gsrc + (((t + 2) & 31) << 12), &bstage[stg * TILEB + wave * 1024]);

        const unsigned char* rb = &bstage[cur * TILEB + m * ROWB];
        bf16x8 c1 = *(const bf16x8*)(rb + ((q * 16) ^ xm));
        bf16x8 c2 = *(const bf16x8*)(rb + ((64 + q * 16) ^ xm));
        bf16x8 c3 = *(const bf16x8*)(rb + ((128 + q * 16) ^ xm));
        bf16x8 c4 = *(const bf16x8*)(rb + ((192 + q * 16) ^ xm));

        const float mh = csqn2_sh[t * 16 + m];
        const f32x4 ci = {mh, mh, mh, mh};
        const int nidx = t * 16 + m;
#pragma unroll
        for (int mt = 0; mt < MT; ++mt) {
            f32x4 accA = __builtin_amdgcn_mfma_f32_16x16x32_bf16(ah1[mt], c1, zero4, 0, 0, 0);
            f32x4 accB = __builtin_amdgcn_mfma_f32_16x16x32_bf16(ah2[mt], c2, ci, 0, 0, 0);
            accA = __builtin_amdgcn_mfma_f32_16x16x32_bf16(al1[mt], c1, accA, 0, 0, 0);
            accB = __builtin_amdgcn_mfma_f32_16x16x32_bf16(al2[mt], c2, accB, 0, 0, 0);
            accA = __builtin_amdgcn_mfma_f32_16x16x32_bf16(ah1[mt], c3, accA, 0, 0, 0);
            accB = __builtin_amdgcn_mfma_f32_16x16x32_bf16(ah2[mt], c4, accB, 0, 0, 0);
#pragma unroll
            for (int r = 0; r < 4; ++r) {
                const int st = mt * 4 + r;
                float u = accA[r] + accB[r];
                bool gt = u > t1u[st];                          // strict: first index wins
                t2u[st] = fminf(fmaxf(u, t2u[st]), t1u[st]);    // 2nd-largest
                t1u[st] = fmaxf(t1u[st], u);
                t1i[st] = gt ? nidx : t1i[st];
            }
        }
        cur = (cur == 2) ? 0 : cur + 1;
        stg = (stg == 2) ? 0 : stg + 1;
    }

    // ---- convert to score space (sc = -2u) and butterfly-merge 16 columns ----
    float t1s[8], t2s[8];
    unsigned long long pk[8];
#pragma unroll
    for (int st = 0; st < 8; ++st) {
        t1s[st] = -2.0f * t1u[st];
        t2s[st] = -2.0f * t2u[st];
        unsigned u = __float_as_uint(t1s[st]);
        unsigned mono = (u & 0x80000000u) ? ~u : (u | 0x80000000u);
        pk[st] = ((unsigned long long)mono << 32) | (unsigned)t1i[st];
    }
#pragma unroll
    for (int dd = 1; dd <= 8; dd <<= 1) {
#pragma unroll
        for (int st = 0; st < 8; ++st) {
            unsigned long long opk = __shfl_xor(pk[st], dd, 64);
            float o1 = __shfl_xor(t1s[st], dd, 64);
            float o2 = __shfl_xor(t2s[st], dd, 64);
            t2s[st] = fminf(fmaxf(t1s[st], o1), fminf(t2s[st], o2));
            t1s[st] = fminf(t1s[st], o1);
            pk[st] = opk < pk[st] ? opk : pk[st];
        }
    }

    // ---- writers: lanes m<8 own state st=m -> vector wave*32+(m>>2)*16+q*4+(m&3)
    float w1s = 3.4e38f, w2s = 3.4e38f;
    unsigned long long wpk = 0;
#pragma unroll
    for (int i = 0; i < 8; ++i) {
        bool sel = (m == i);
        w1s = sel ? t1s[i] : w1s;
        w2s = sel ? t2s[i] : w2s;
        wpk = sel ? pk[i] : wpk;
    }
    const bool writer = (m < 8);
    const int vloc = wave * 32 + ((m >> 2) & 1) * 16 + q * 4 + (m & 3);
    float dl = 0.f;
    if (writer) {
        zsh[vloc] = (int)(wpk & 0xffffffffull);
        if (w2s - w1s <= GAP_THRESH) {
            int pos = atomicAdd(&rn, 1);
            rlist[pos] = vloc;
        }
        float full = vsq_all[vloc] + w1s;          // loss = relu(vsq + best)
        dl = (full < 0.f ? 0.f : full) * inv_n;
    }
#pragma unroll
    for (int off = 32; off >= 1; off >>= 1) dl += __shfl_down(dl, off, 64);
    if (lane == 0) atomicAdd(&loss_sh, dl);

    __syncthreads();

    // ---- in-block exact rescue (r3-proven arithmetic): wave w -> rlist[base+w]
    const int nr = rn;
    for (int rbase = 0; rbase < nr; rbase += 4) {
        const int slot = rbase + wave;
        if (slot < nr) {                       // wave-uniform
            const int rv = rlist[slot];
            const float4* vrow4 = (const float4*)(vecs + (size_t)(blockbase + rv) * VQ_K);
            const float vsqr = vsq_all[rv];
            unsigned long long best = ~0ull;
            for (int j = 0; j < 8; ++j) {
                const int s = lane * 8 + j;
                const float4* crow = (const float4*)(codebook + (size_t)s * VQ_K);
                double acc = 0.0;
#pragma unroll
                for (int qq = 0; qq < VQ_K / 4; ++qq) {
                    float4 c = crow[qq];
                    float4 tt = vrow4[qq];     // wave-uniform -> scalar loads
                    acc = fma((double)c.x, (double)tt.x, acc);
                    acc = fma((double)c.y, (double)tt.y, acc);
                    acc = fma((double)c.z, (double)tt.z, acc);
                    acc = fma((double)c.w, (double)tt.w, acc);
                }
                float e = (float)acc;
                float sc = fmaf(-2.0f, e, vsqr) + csq_sh[s];   // exact ref rounding
                unsigned u = __float_as_uint(sc);
                unsigned mono = (u & 0x80000000u) ? ~u : (u | 0x80000000u);
                unsigned long long pkr = ((unsigned long long)mono << 32) | (unsigned)s;
                best = pkr < best ? pkr : best;
            }
#pragma unroll
            for (int off = 32; off >= 1; off >>= 1) {
                unsigned long long o = __shfl_down(best, off, 64);
                best = o < best ? o : best;
            }
            if (lane == 0) zsh[rv] = (int)(best & 0xffffffffull);
        }
    }
    __syncthreads();

    // ---- loss atomics (2/block), coalesced z write + gather ----
    if (tid == 0) {
        float l = loss_sh;
        atomicAdd(&out_loss[0], l);
        atomicAdd(&out_loss[1], l);
    }
    if (tid < VPB) out_z[blockbase + tid] = (float)zsh[tid];
    const float4* cb4g = (const float4*)codebook;
    float4* hat4 = (float4*)(out_hat + (size_t)blockbase * VQ_K);
    const int F = VPB * (VQ_K / 4);                // 2048
#pragma unroll
    for (int f = tid; f < F; f += NTHREADS) {
        int vv = f >> 4;
        int k4 = f & 15;
        hat4[f] = cb4g[zsh[vv] * (VQ_K / 4) + k4];
    }
}

extern "C" void kernel_launch(void* const* d_in, const int* in_sizes, int n_in,
                              void* d_out, int out_size, void* d_ws, size_t ws_size,
                              hipStream_t stream) {
    const float* vecs = (const float*)d_in[0];
    const float* codebook = (const float*)d_in[1];
    float* out = (float*)d_out;

    const int nvec = in_sizes[0] / VQ_K;            // 65536
    unsigned char* bimg = (unsigned char*)d_ws;     // 133120 B image (+ slack)

    float* out_hat = out;
    float* out_z = out + (size_t)nvec * VQ_K;
    float* out_loss = out + out_size - 2;

    vq_prep<<<VQ_S / 4, 256, 0, stream>>>(codebook, bimg, out_loss);
    vq_mfma<<<nvec / VPB, NTHREADS, 0, stream>>>(
        vecs, codebook, bimg, out_hat, out_z, out_loss, 1.0f / (float)nvec);
}

// Round 5
// 104.266 us; speedup vs baseline: 1.0881x; 1.0881x over previous
//
#include <hip/hip_runtime.h>
#include <hip/hip_bf16.h>
#include <stdint.h>

// SimpleVectorQuantizer: vecs [16,32,128,64] f32, codebook [512,64] f32.
// Outputs (flat f32): vecs_hat [65536*64], z [65536] (as float), l_commit, l_codebook.
//
// Round 16: r11/r14/r15 all land 44-52us despite three different B-delivery
// schemes (L2 stream / depth-3 reg pipeline / LDS staging) -- every variant
// still touches global memory in the K-loop through a thrashing 32KB L1.
// The split-B image is 131KB and FITS IN LDS (160KB/CU). New structure:
// ONE 512-thread block per CU (grid=256, VPB=256, 8 waves x MT=2, per-wave
// work identical to r11). Prologue: each thread converts 1 codebook row to
// hi/lo bf16 and ds_writes it swizzled into a resident LDS image (we control
// the write now, so swizzle is both-sides per rule #21). One syncthreads,
// then the K-loop is BARRIER-FREE and GLOBAL-FREE: ds_read_b128 + MFMA +
// ranking only (1MB LDS read/CU ~ 8K cyc). No second block round (1/CU).
// bimg workspace dies; vq_prep shrinks to csq-only. Byte layout + XOR
// swizzle ((row&7)<<4 on 16B slots) identical to r15's absmax-0 path;
// merge / writers / in-block exact-f64 rescue / gather unchanged.

#define VQ_K 64
#define VQ_S 512
#define NTHREADS 512                     // 8 waves
#define MT 2                             // m-tiles per wave -> 32 vectors/wave
#define VPB 256                          // vectors per block
#define NTILES 32                        // 512 codewords / 16 per tile
#define ROWB 256                         // B row: 64 hi bf16 + 64 lo bf16 (packed)
#define CELL 7.62939453125e-6f           // f32 ulp at ref-score magnitude ~64
#define GAP_THRESH (8.0f * CELL)

typedef __attribute__((ext_vector_type(8))) short bf16x8;
typedef __attribute__((ext_vector_type(4))) float f32x4;

static __device__ __forceinline__ unsigned short f2bf_rne(float f) {
    unsigned u = __float_as_uint(f);
    unsigned r = (u + 0x7fffu + ((u >> 16) & 1u)) >> 16;
    return (unsigned short)r;
}
static __device__ __forceinline__ float bf2f(unsigned short h) {
    return __uint_as_float(((unsigned)h) << 16);
}

// K1: one wave per codebook row; lane k handles element k. csq only + zero loss.
__global__ __launch_bounds__(256, 1) void vq_prep(
    const float* __restrict__ cb, float* __restrict__ csqg,
    float* __restrict__ out_loss) {
    if (blockIdx.x == 0 && threadIdx.x == 0) { out_loss[0] = 0.f; out_loss[1] = 0.f; }
    const int lane = threadIdx.x & 63;
    const int row = blockIdx.x * 4 + (threadIdx.x >> 6);
    float c = cb[(size_t)row * VQ_K + lane];
    double d = (double)c * (double)c;
#pragma unroll
    for (int off = 1; off <= 32; off <<= 1) d += __shfl_xor(d, off, 64);
    if (lane == 0) csqg[row] = (float)d;
}

// K2: all-LDS-resident B image, barrier-free MFMA scan + in-block exact rescue.
__global__ __launch_bounds__(NTHREADS, 1) void vq_mfma(
    const float* __restrict__ vecs, const float* __restrict__ codebook,
    const float* __restrict__ csqg,
    float* __restrict__ out_hat, float* __restrict__ out_z,
    float* __restrict__ out_loss, float inv_n) {
    __shared__ __align__(16) unsigned char blds[VQ_S * ROWB];  // 131072 B
    __shared__ float csq_sh[VQ_S];       // exact csq (rescue)
    __shared__ float csqn2_sh[VQ_S];     // -csq/2 (C-init for the scan)
    __shared__ float vsq_all[VPB];
    __shared__ int zsh[VPB];
    __shared__ int rlist[VPB];
    __shared__ int rn;
    __shared__ float loss_sh;

    const int tid = threadIdx.x;
    const int wave = tid >> 6;                    // 0..7
    const int lane = tid & 63;
    const int m = lane & 15;
    const int q = lane >> 4;
    const int blockbase = blockIdx.x * VPB;
    const int wavebase = blockbase + wave * 32;   // 32 vectors per wave

    if (tid == 0) { rn = 0; loss_sh = 0.f; }
    // csq tables: 512 entries, 512 threads -> 1 each.
    {
        float c = csqg[tid];
        csq_sh[tid] = c;
        csqn2_sh[tid] = -0.5f * c;
    }
    // B image: thread t converts codebook row t into swizzled LDS (hi|lo).
    {
        const int row = tid;
        const float4* crow = (const float4*)(codebook + (size_t)row * VQ_K);
        const int xr = (row & 7) << 4;
        unsigned char* rowp = &blds[row * ROWB];
#pragma unroll
        for (int j = 0; j < 8; ++j) {             // 8 chunks of 8 elems
            float4 f0 = crow[2 * j];
            float4 f1 = crow[2 * j + 1];
            float w[8] = {f0.x, f0.y, f0.z, f0.w, f1.x, f1.y, f1.z, f1.w};
            bf16x8 hi8, lo8;
#pragma unroll
            for (int e = 0; e < 8; ++e) {
                unsigned short h = f2bf_rne(w[e]);
                hi8[e] = (short)h;
                lo8[e] = (short)f2bf_rne(w[e] - bf2f(h));
            }
            *(bf16x8*)(rowp + ((j * 16) ^ xr)) = hi8;          // hi: bytes [0,128)
            *(bf16x8*)(rowp + (128 + ((j * 16) ^ xr))) = lo8;  // lo: bytes [128,256)
        }
    }

    // ---- A fragments (bf16 split) + exact vsq ----
    bf16x8 ah1[MT], ah2[MT], al1[MT], al2[MT];
#pragma unroll
    for (int mt = 0; mt < MT; ++mt) {
        const float* vp = vecs + (size_t)(wavebase + mt * 16 + m) * VQ_K + q * 8;
        float4 a0 = ((const float4*)vp)[0];
        float4 a1 = ((const float4*)vp)[1];
        float4 b0 = ((const float4*)(vp + 32))[0];
        float4 b1 = ((const float4*)(vp + 32))[1];
        float w1[8] = {a0.x, a0.y, a0.z, a0.w, a1.x, a1.y, a1.z, a1.w};
        float w2[8] = {b0.x, b0.y, b0.z, b0.w, b1.x, b1.y, b1.z, b1.w};
        double p = 0.0;
#pragma unroll
        for (int j = 0; j < 8; ++j) {
            double d1 = (double)w1[j], d2 = (double)w2[j];
            p = fma(d1, d1, p); p = fma(d2, d2, p);
        }
        p += __shfl_xor(p, 16, 64);
        p += __shfl_xor(p, 32, 64);
        if (q == 0) vsq_all[wave * 32 + mt * 16 + m] = (float)p;
#pragma unroll
        for (int j = 0; j < 8; ++j) {
            unsigned short h1 = f2bf_rne(w1[j]);
            unsigned short h2 = f2bf_rne(w2[j]);
            ah1[mt][j] = (short)h1;
            ah2[mt][j] = (short)h2;
            al1[mt][j] = (short)f2bf_rne(w1[j] - bf2f(h1));
            al2[mt][j] = (short)f2bf_rne(w2[j] - bf2f(h2));
        }
    }
    __syncthreads();   // B image + csq tables + vsq resident

    // ---- K-loop: pure LDS + MFMA + ranking. No barriers, no global. ----
    float t1u[8], t2u[8];
    int t1i[8];
#pragma unroll
    for (int st = 0; st < 8; ++st) { t1u[st] = -3.4e38f; t2u[st] = -3.4e38f; t1i[st] = 0; }
    const f32x4 zero4 = {0.f, 0.f, 0.f, 0.f};
    const int xm = (m & 7) << 4;

#pragma unroll 4
    for (int t = 0; t < NTILES; ++t) {
        const unsigned char* rb = &blds[(t * 16 + m) * ROWB];
        bf16x8 c1 = *(const bf16x8*)(rb + ((q * 16) ^ xm));
        bf16x8 c2 = *(const bf16x8*)(rb + ((64 + q * 16) ^ xm));
        bf16x8 c3 = *(const bf16x8*)(rb + (128 + ((q * 16) ^ xm)));
        bf16x8 c4 = *(const bf16x8*)(rb + (128 + ((64 + q * 16) ^ xm)));

        const float mh = csqn2_sh[t * 16 + m];
        const f32x4 ci = {mh, mh, mh, mh};
        const int nidx = t * 16 + m;
#pragma unroll
        for (int mt = 0; mt < MT; ++mt) {
            f32x4 accA = __builtin_amdgcn_mfma_f32_16x16x32_bf16(ah1[mt], c1, zero4, 0, 0, 0);
            f32x4 accB = __builtin_amdgcn_mfma_f32_16x16x32_bf16(ah2[mt], c2, ci, 0, 0, 0);
            accA = __builtin_amdgcn_mfma_f32_16x16x32_bf16(al1[mt], c1, accA, 0, 0, 0);
            accB = __builtin_amdgcn_mfma_f32_16x16x32_bf16(al2[mt], c2, accB, 0, 0, 0);
            accA = __builtin_amdgcn_mfma_f32_16x16x32_bf16(ah1[mt], c3, accA, 0, 0, 0);
            accB = __builtin_amdgcn_mfma_f32_16x16x32_bf16(ah2[mt], c4, accB, 0, 0, 0);
#pragma unroll
            for (int r = 0; r < 4; ++r) {
                const int st = mt * 4 + r;
                float u = accA[r] + accB[r];
                bool gt = u > t1u[st];                          // strict: first index wins
                t2u[st] = fminf(fmaxf(u, t2u[st]), t1u[st]);    // 2nd-largest
                t1u[st] = fmaxf(t1u[st], u);
                t1i[st] = gt ? nidx : t1i[st];
            }
        }
    }

    // ---- convert to score space (sc = -2u) and butterfly-merge 16 columns ----
    float t1s[8], t2s[8];
    unsigned long long pk[8];
#pragma unroll
    for (int st = 0; st < 8; ++st) {
        t1s[st] = -2.0f * t1u[st];
        t2s[st] = -2.0f * t2u[st];
        unsigned u = __float_as_uint(t1s[st]);
        unsigned mono = (u & 0x80000000u) ? ~u : (u | 0x80000000u);
        pk[st] = ((unsigned long long)mono << 32) | (unsigned)t1i[st];
    }
#pragma unroll
    for (int dd = 1; dd <= 8; dd <<= 1) {
#pragma unroll
        for (int st = 0; st < 8; ++st) {
            unsigned long long opk = __shfl_xor(pk[st], dd, 64);
            float o1 = __shfl_xor(t1s[st], dd, 64);
            float o2 = __shfl_xor(t2s[st], dd, 64);
            t2s[st] = fminf(fmaxf(t1s[st], o1), fminf(t2s[st], o2));
            t1s[st] = fminf(t1s[st], o1);
            pk[st] = opk < pk[st] ? opk : pk[st];
        }
    }

    // ---- writers: lanes m<8 own state st=m -> vector wave*32+(m>>2)*16+q*4+(m&3)
    float w1s = 3.4e38f, w2s = 3.4e38f;
    unsigned long long wpk = 0;
#pragma unroll
    for (int i = 0; i < 8; ++i) {
        bool sel = (m == i);
        w1s = sel ? t1s[i] : w1s;
        w2s = sel ? t2s[i] : w2s;
        wpk = sel ? pk[i] : wpk;
    }
    const bool writer = (m < 8);
    const int vloc = wave * 32 + ((m >> 2) & 1) * 16 + q * 4 + (m & 3);
    float dl = 0.f;
    if (writer) {
        zsh[vloc] = (int)(wpk & 0xffffffffull);
        if (w2s - w1s <= GAP_THRESH) {
            int pos = atomicAdd(&rn, 1);
            rlist[pos] = vloc;
        }
        float full = vsq_all[vloc] + w1s;          // loss = relu(vsq + best)
        dl = (full < 0.f ? 0.f : full) * inv_n;
    }
#pragma unroll
    for (int off = 32; off >= 1; off >>= 1) dl += __shfl_down(dl, off, 64);
    if (lane == 0) atomicAdd(&loss_sh, dl);

    __syncthreads();

    // ---- in-block exact rescue (r3-proven arithmetic): wave w -> rlist[base+w]
    const int nr = rn;
    for (int rbase = 0; rbase < nr; rbase += 8) {
        const int slot = rbase + wave;
        if (slot < nr) {                       // wave-uniform
            const int rv = rlist[slot];
            const float4* vrow4 = (const float4*)(vecs + (size_t)(blockbase + rv) * VQ_K);
            const float vsqr = vsq_all[rv];
            unsigned long long best = ~0ull;
            for (int j = 0; j < 8; ++j) {
                const int s = lane * 8 + j;
                const float4* crow = (const float4*)(codebook + (size_t)s * VQ_K);
                double acc = 0.0;
#pragma unroll
                for (int qq = 0; qq < VQ_K / 4; ++qq) {
                    float4 c = crow[qq];
                    float4 tt = vrow4[qq];     // wave-uniform -> scalar loads
                    acc = fma((double)c.x, (double)tt.x, acc);
                    acc = fma((double)c.y, (double)tt.y, acc);
                    acc = fma((double)c.z, (double)tt.z, acc);
                    acc = fma((double)c.w, (double)tt.w, acc);
                }
                float e = (float)acc;
                float sc = fmaf(-2.0f, e, vsqr) + csq_sh[s];   // exact ref rounding
                unsigned u = __float_as_uint(sc);
                unsigned mono = (u & 0x80000000u) ? ~u : (u | 0x80000000u);
                unsigned long long pkr = ((unsigned long long)mono << 32) | (unsigned)s;
                best = pkr < best ? pkr : best;
            }
#pragma unroll
            for (int off = 32; off >= 1; off >>= 1) {
                unsigned long long o = __shfl_down(best, off, 64);
                best = o < best ? o : best;
            }
            if (lane == 0) zsh[rv] = (int)(best & 0xffffffffull);
        }
    }
    __syncthreads();

    // ---- loss atomics (2/block), coalesced z write + gather ----
    if (tid == 0) {
        float l = loss_sh;
        atomicAdd(&out_loss[0], l);
        atomicAdd(&out_loss[1], l);
    }
    if (tid < VPB) out_z[blockbase + tid] = (float)zsh[tid];
    const float4* cb4g = (const float4*)codebook;
    float4* hat4 = (float4*)(out_hat + (size_t)blockbase * VQ_K);
    const int F = VPB * (VQ_K / 4);                // 4096
#pragma unroll
    for (int f = tid; f < F; f += NTHREADS) {
        int vv = f >> 4;
        int k4 = f & 15;
        hat4[f] = cb4g[zsh[vv] * (VQ_K / 4) + k4];
    }
}

extern "C" void kernel_launch(void* const* d_in, const int* in_sizes, int n_in,
                              void* d_out, int out_size, void* d_ws, size_t ws_size,
                              hipStream_t stream) {
    const float* vecs = (const float*)d_in[0];
    const float* codebook = (const float*)d_in[1];
    float* out = (float*)d_out;

    const int nvec = in_sizes[0] / VQ_K;            // 65536
    float* csqg = (float*)d_ws;                     // 2048 B

    float* out_hat = out;
    float* out_z = out + (size_t)nvec * VQ_K;
    float* out_loss = out + out_size - 2;

    vq_prep<<<VQ_S / 4, 256, 0, stream>>>(codebook, csqg, out_loss);
    vq_mfma<<<nvec / VPB, NTHREADS, 0, stream>>>(
        vecs, codebook, csqg, out_hat, out_z, out_loss, 1.0f / (float)nvec);
}